// Round 1
// baseline (288.860 us; speedup 1.0000x reference)
//
#include <hip/hip_runtime.h>
#include <math.h>

#define ALPHA 0.001f
#define EPS 1e-12f
#define IN_DIM 8192
#define OUT_DIM 4096
#define COL4 (IN_DIM / 4)     // 2048 float4 per row
#define NSEG 64
#define SEG_ROWS (OUT_DIM / NSEG) // 64

// ---------------- Kernel 1: y = W @ x (unnormalized), one wave per row ----
__global__ __launch_bounds__(256) void k_matvec(const float* __restrict__ W,
                                                const float* __restrict__ x,
                                                float* __restrict__ y) {
    const int wave = threadIdx.x >> 6;
    const int lane = threadIdx.x & 63;
    const int row = blockIdx.x * 4 + wave;
    const float4* Wr = (const float4*)(W + (size_t)row * IN_DIM);
    const float4* xv = (const float4*)x;
    float acc = 0.0f;
#pragma unroll 8
    for (int c = 0; c < COL4 / 64; ++c) {       // 32 float4 per lane
        float4 w = Wr[lane + c * 64];
        float4 xx = xv[lane + c * 64];
        acc += w.x * xx.x + w.y * xx.y + w.z * xx.z + w.w * xx.w;
    }
#pragma unroll
    for (int off = 32; off; off >>= 1) acc += __shfl_xor(acc, off, 64);
    if (lane == 0) y[row] = acc;
}

// ---------------- Kernel 2: normalize; write y_n to out, yv to ws ---------
__global__ __launch_bounds__(256) void k_norm(const float* __restrict__ y,
                                              float* __restrict__ yn_out,
                                              float* __restrict__ yv_ws) {
    __shared__ float red[4];
    float s = 0.0f;
    for (int i = threadIdx.x; i < OUT_DIM; i += 256) {
        float v = y[i];
        s += v * v;
    }
#pragma unroll
    for (int off = 32; off; off >>= 1) s += __shfl_xor(s, off, 64);
    const int wave = threadIdx.x >> 6;
    const int lane = threadIdx.x & 63;
    if (lane == 0) red[wave] = s;
    __syncthreads();
    const float tot = red[0] + red[1] + red[2] + red[3];
    const float inv = 1.0f / fmaxf(sqrtf(tot), EPS);
    for (int i = threadIdx.x; i < OUT_DIM; i += 256) {
        float v = y[i] * inv;
        yn_out[i] = v;
        yv_ws[i] = v;
    }
}

// ---------------- Kernel 3: per-segment column sums P[s][i] ---------------
// grid: (IN_DIM/1024 = 8, NSEG); block 256; 4 cols (1 float4) per thread
__global__ __launch_bounds__(256) void k_pseg(const float* __restrict__ W,
                                              const float* __restrict__ yv,
                                              float* __restrict__ P) {
    const int seg = blockIdx.y;
    const int col4 = blockIdx.x * 256 + threadIdx.x;  // 0..COL4-1
    const float4* Wp = (const float4*)W;
    const int j0 = seg * SEG_ROWS;
    float4 acc = make_float4(0.f, 0.f, 0.f, 0.f);
#pragma unroll 4
    for (int j = 0; j < SEG_ROWS; ++j) {
        const float yj = yv[j0 + j];
        float4 w = Wp[(size_t)(j0 + j) * COL4 + col4];
        acc.x += w.x * yj;
        acc.y += w.y * yj;
        acc.z += w.z * yj;
        acc.w += w.w * yj;
    }
    ((float4*)P)[(size_t)seg * COL4 + col4] = acc;
}

// ---------------- Kernel 4: exclusive scan of P over segments, in place ---
// grid: COL4/256 = 8 blocks
__global__ __launch_bounds__(256) void k_scan(float* __restrict__ P) {
    const int col4 = blockIdx.x * 256 + threadIdx.x;
    float4* Pp = (float4*)P;
    float4 run = make_float4(0.f, 0.f, 0.f, 0.f);
#pragma unroll 4
    for (int s = 0; s < NSEG; ++s) {
        float4 v = Pp[(size_t)s * COL4 + col4];
        Pp[(size_t)s * COL4 + col4] = run;
        run.x += v.x;
        run.y += v.y;
        run.z += v.z;
        run.w += v.w;
    }
}

// ---------------- Kernel 5: local inclusive scan + Hebbian update ---------
// grid: (8, NSEG); block 256
__global__ __launch_bounds__(256) void k_update(const float* __restrict__ W,
                                                const float* __restrict__ x,
                                                const float* __restrict__ yv,
                                                const float* __restrict__ E,
                                                float* __restrict__ Wout) {
    const int seg = blockIdx.y;
    const int col4 = blockIdx.x * 256 + threadIdx.x;
    const float4* Wp = (const float4*)W;
    float4* Op = (float4*)Wout;
    float4 run = ((const float4*)E)[(size_t)seg * COL4 + col4];
    const float4 x4 = ((const float4*)x)[col4];
    const int j0 = seg * SEG_ROWS;
#pragma unroll 4
    for (int j = 0; j < SEG_ROWS; ++j) {
        const float yj = yv[j0 + j];
        const size_t idx = (size_t)(j0 + j) * COL4 + col4;
        float4 w = Wp[idx];
        run.x += w.x * yj;
        run.y += w.y * yj;
        run.z += w.z * yj;
        run.w += w.w * yj;
        float4 o;
        o.x = w.x + ALPHA * (yj * x4.x - yj * run.x);
        o.y = w.y + ALPHA * (yj * x4.y - yj * run.y);
        o.z = w.z + ALPHA * (yj * x4.z - yj * run.z);
        o.w = w.w + ALPHA * (yj * x4.w - yj * run.w);
        Op[idx] = o;
    }
}

extern "C" void kernel_launch(void* const* d_in, const int* in_sizes, int n_in,
                              void* d_out, int out_size, void* d_ws, size_t ws_size,
                              hipStream_t stream) {
    const float* x = (const float*)d_in[0];   // [8192]
    const float* W = (const float*)d_in[1];   // [4096, 8192]
    float* out = (float*)d_out;
    float* yn_out = out;                      // [4096]
    float* Wout = out + OUT_DIM;              // [4096*8192]

    // workspace layout (floats): y/yv [4096] | P [NSEG*IN_DIM]
    float* y = (float*)d_ws;
    float* P = y + OUT_DIM;

    // 1. y = W @ x
    k_matvec<<<dim3(OUT_DIM / 4), dim3(256), 0, stream>>>(W, x, y);
    // 2. normalize (yv overwrites y in ws; also written to d_out)
    k_norm<<<dim3(1), dim3(256), 0, stream>>>(y, yn_out, y);
    // 3. per-segment partial column sums
    k_pseg<<<dim3(COL4 / 256, NSEG), dim3(256), 0, stream>>>(W, y, P);
    // 4. exclusive scan over segments (in place)
    k_scan<<<dim3(COL4 / 256), dim3(256), 0, stream>>>(P);
    // 5. local scan + update
    k_update<<<dim3(COL4 / 256, NSEG), dim3(256), 0, stream>>>(W, x, y, P, Wout);
}